// Round 3
// baseline (508.237 us; speedup 1.0000x reference)
//
#include <hip/hip_runtime.h>

typedef __bf16 bf16;
typedef __bf16 bf16x8 __attribute__((ext_vector_type(8)));
typedef unsigned short u16x8 __attribute__((ext_vector_type(8)));
typedef float f32x4 __attribute__((ext_vector_type(4)));

#define HH 128
#define WW 128
#define HP 130   // padded extent

// ---------------------------------------------------------------------------
// Pad+transpose  [b][ci][y][x] f32  ->  [b][y+1][x+1][ci] bf16 (ring pre-zeroed)
// ---------------------------------------------------------------------------
__global__ __launch_bounds__(256) void transpose_pad(const float* __restrict__ in,
                                                     bf16* __restrict__ out) {
  __shared__ float tile[64][65];
  const int b = blockIdx.z, y = blockIdx.y, x0 = blockIdx.x * 64;
  const int tid = threadIdx.x;
#pragma unroll
  for (int pass = 0; pass < 16; ++pass) {
    int ci = pass * 4 + (tid >> 6);
    int x = tid & 63;
    tile[ci][x] = in[((b * 64 + ci) * HH + y) * WW + x0 + x];
  }
  __syncthreads();
#pragma unroll
  for (int pass = 0; pass < 16; ++pass) {
    int x = pass * 4 + (tid >> 6);
    int ci = tid & 63;
    out[((size_t)(b * HP + (y + 1)) * HP + (x0 + x + 1)) * 64 + ci] = (bf16)tile[ci][x];
  }
}

// Same but f32 output (deformable-gather source xp)
__global__ __launch_bounds__(256) void transpose_pad_f32(const float* __restrict__ in,
                                                         float* __restrict__ out) {
  __shared__ float tile[64][65];
  const int b = blockIdx.z, y = blockIdx.y, x0 = blockIdx.x * 64;
  const int tid = threadIdx.x;
#pragma unroll
  for (int pass = 0; pass < 16; ++pass) {
    int ci = pass * 4 + (tid >> 6);
    int x = tid & 63;
    tile[ci][x] = in[((b * 64 + ci) * HH + y) * WW + x0 + x];
  }
  __syncthreads();
#pragma unroll
  for (int pass = 0; pass < 16; ++pass) {
    int x = pass * 4 + (tid >> 6);
    int ci = tid & 63;
    out[((size_t)(b * HP + (y + 1)) * HP + (x0 + x + 1)) * 64 + ci] = tile[ci][x];
  }
}

// ---------------------------------------------------------------------------
// Pack conv weights into MFMA B-fragment layout.
// ---------------------------------------------------------------------------
__global__ void build_bfrag(const float* __restrict__ W1, int n1,
                            const float* __restrict__ W2, int n2,
                            bf16* __restrict__ dst, int ntiles) {
  int idx = blockIdx.x * 256 + threadIdx.x;
  int total = ntiles * 18 * 64;
  if (idx >= total) return;
  int lane = idx & 63;
  int kc = (idx >> 6) % 18;
  int n = (idx / (64 * 18)) * 16 + (lane & 15);
  int q = lane >> 4;
  bf16x8 v;
#pragma unroll
  for (int j = 0; j < 8; ++j) {
    int k = kc * 32 + q * 8 + j;
    int tap = k >> 6, ci = k & 63;
    float w = 0.f;
    if (n < n1) w = W1[(n * 64 + ci) * 9 + tap];
    else if (n < n1 + n2) w = W2[((n - n1) * 64 + ci) * 9 + tap];
    v[j] = (bf16)w;
  }
  *reinterpret_cast<bf16x8*>(dst + (size_t)idx * 8) = v;
}

// ---------------------------------------------------------------------------
// GEMM core, 16x16 pixel tile (M=256), XOR-swizzled A patch in LDS.
// ---------------------------------------------------------------------------
template <int NT>
__device__ __forceinline__ void gemm16(const bf16* __restrict__ At,
                                       const bf16* __restrict__ BfBase,
                                       int b, int h0, int w0,
                                       f32x4 (&acc)[4][NT], ushort* apatch) {
  const int tid = threadIdx.x;
  const int lane = tid & 63;
  const int wv = tid >> 6;
  const int q = lane >> 4;
  const int col = lane & 15;
  const ushort* Atu = reinterpret_cast<const ushort*>(At);

#pragma unroll
  for (int it = 0; it < 11; ++it) {
    int flat = it * 256 + tid;
    if (flat < 2592) {
      int px = flat >> 3, c8 = flat & 7;
      int py = px / 18, pxx = px - py * 18;
      u16x8 v = *reinterpret_cast<const u16x8*>(
          Atu + ((size_t)((b * HP + h0 + py) * HP + (w0 + pxx))) * 64 + c8 * 8);
      *reinterpret_cast<u16x8*>(apatch + px * 64 + ((c8 ^ (px & 7)) * 8)) = v;
    }
  }
  __syncthreads();

  const bf16* bl = BfBase + lane * 8;
  for (int dh = 0; dh < 3; ++dh) {
#pragma unroll
    for (int dw = 0; dw < 3; ++dw) {
      const int tap = dh * 3 + dw;
      bf16x8 a[4][2];
#pragma unroll
      for (int s = 0; s < 4; ++s) {
        int p = (s * 4 + wv + dh) * 18 + (col + dw);
#pragma unroll
        for (int half = 0; half < 2; ++half) {
          int ch = (half * 4 + q) ^ (p & 7);
          a[s][half] = *reinterpret_cast<const bf16x8*>(
              reinterpret_cast<const bf16*>(apatch) + p * 64 + ch * 8);
        }
      }
#pragma unroll
      for (int half = 0; half < 2; ++half) {
        const bf16* bp = bl + (tap * 2 + half) * 512;
#pragma unroll
        for (int nt = 0; nt < NT; ++nt) {
          bf16x8 bb = *reinterpret_cast<const bf16x8*>(bp + (size_t)nt * 9216);
#pragma unroll
          for (int s = 0; s < 4; ++s)
            acc[s][nt] = __builtin_amdgcn_mfma_f32_16x16x32_bf16(a[s][half], bb, acc[s][nt], 0, 0, 0);
        }
      }
    }
  }
}

// ---------------------------------------------------------------------------
// offset(18) + mask(9, sigmoid) conv from feature_size.
// ---------------------------------------------------------------------------
__global__ __launch_bounds__(256, 4) void conv_offm(const bf16* __restrict__ fs_t,
                                                    const bf16* __restrict__ Bf2,
                                                    const float* __restrict__ pb,
                                                    const float* __restrict__ mb,
                                                    float* __restrict__ off_buf,
                                                    float* __restrict__ m_buf) {
  __shared__ __align__(16) ushort apatch[324 * 64];
  const int bid = blockIdx.x;
  const int b = bid >> 6;
  const int t = bid & 63;
  const int h0 = (t >> 3) * 16, w0 = (t & 7) * 16;
  f32x4 acc[4][2];
#pragma unroll
  for (int s = 0; s < 4; ++s)
#pragma unroll
    for (int n = 0; n < 2; ++n) acc[s][n] = (f32x4){0.f, 0.f, 0.f, 0.f};
  gemm16<2>(fs_t, Bf2, b, h0, w0, acc, apatch);

  const int lane = threadIdx.x & 63, wv = threadIdx.x >> 6;
  const int q = lane >> 4, col = lane & 15;
#pragma unroll
  for (int s = 0; s < 4; ++s) {
    int h = h0 + s * 4 + wv;
#pragma unroll
    for (int nt = 0; nt < 2; ++nt) {
      int n = nt * 16 + col;
#pragma unroll
      for (int j = 0; j < 4; ++j) {
        int w = w0 + q * 4 + j;
        float v = acc[s][nt][j];
        if (n < 18) {
          off_buf[((b * 18 + n) * HH + h) * WW + w] = v + pb[n];
        } else if (n < 27) {
          float z = v + mb[n - 18];
          m_buf[((b * 9 + (n - 18)) * HH + h) * WW + w] = 1.f / (1.f + __expf(-z));
        }
      }
    }
  }
}

// ---------------------------------------------------------------------------
// PSF conv GEMM -> P (bf16, layout [brel][px][tap][ch]) with bias fused.
// grid = (128 tiles [2 b's], 4 cc chunks)
// ---------------------------------------------------------------------------
__global__ __launch_bounds__(256, 2) void gemm_psf(const bf16* __restrict__ ctx_t,
                                                   const bf16* __restrict__ Bf,
                                                   const float* __restrict__ fb,
                                                   bf16* __restrict__ Pg, int b0) {
  __shared__ __align__(16) ushort apatch[324 * 64];
  const int bid = blockIdx.x;
  const int cc = blockIdx.y;
  const int brel = bid >> 6;
  const int b = b0 + brel;
  const int t = bid & 63;
  const int h0 = (t >> 3) * 16, w0 = (t & 7) * 16;

  f32x4 acc[4][9];
#pragma unroll
  for (int s = 0; s < 4; ++s)
#pragma unroll
    for (int n = 0; n < 9; ++n) acc[s][n] = (f32x4){0.f, 0.f, 0.f, 0.f};
  gemm16<9>(ctx_t, Bf + (size_t)cc * 9 * 9216, b, h0, w0, acc, apatch);

  const int lane = threadIdx.x & 63, wv = threadIdx.x >> 6;
  const int q = lane >> 4, col = lane & 15;
  bf16* Pp = Pg + (size_t)brel * 16384 * 576;
#pragma unroll
  for (int nt = 0; nt < 9; ++nt) {
    int n = cc * 144 + nt * 16 + col;
    float bias = fb[n];
    int c = n / 9;
    int t9 = n - c * 9;
    int noff = t9 * 64 + c;
#pragma unroll
    for (int s = 0; s < 4; ++s) {
      int h = h0 + s * 4 + wv;
#pragma unroll
      for (int j = 0; j < 4; ++j) {
        int w = w0 + q * 4 + j;
        Pp[(size_t)(h * WW + w) * 576 + noff] = (bf16)(acc[s][nt][j] + bias);
      }
    }
  }
}

// ---------------------------------------------------------------------------
// Sampler: wave = pixel, lane = channel. Block = 16 consecutive-w pixels
// (4 waves x 4 px). Bilinear math wave-uniform; corner gathers are coalesced
// 256B; P reads coalesced 128B/tap. Output staged via LDS -> 64B-line stores.
// grid = 2048 blocks per 2-b batch.
// ---------------------------------------------------------------------------
__global__ __launch_bounds__(256) void sampler(const bf16* __restrict__ Pg,
                                               const float* __restrict__ xp,
                                               const float* __restrict__ off_buf,
                                               const float* __restrict__ m_buf,
                                               float* __restrict__ out, int b0) {
  __shared__ float smem[64][20];
  const int tid = threadIdx.x;
  const int wv = tid >> 6;
  const int c = tid & 63;
  const int blk = blockIdx.x;          // 0..2047
  const int brel = blk >> 10;
  const int b = b0 + brel;
  const int h = (blk >> 3) & 127;
  const int w0 = (blk & 7) * 16;

  const float* xpb = xp + (size_t)b * (HP * HP * 64) + c;
  const bf16* Pbase = Pg + ((size_t)brel * 16384 + h * WW + w0) * 576;

  for (int k = 0; k < 4; ++k) {
    const int pl = wv * 4 + k;         // pixel local 0..15
    const int w = w0 + pl;
    const bf16* Pp = Pbase + (size_t)pl * 576;
    float res = 0.f;
#pragma unroll
    for (int i3 = 0; i3 < 3; ++i3) {
#pragma unroll
      for (int j3 = 0; j3 < 3; ++j3) {
        const int dh = (i3 == 0) ? -1 : 0, ri = (i3 == 0) ? 2 : (i3 - 1);
        const int dw = (j3 == 0) ? -1 : 0, rj = (j3 == 0) ? 2 : (j3 - 1);
        const int hh = h + dh, ww2 = w + dw;
        if (hh < 0 || ww2 < 0) continue;     // wave-uniform branch
        const int np = ri * 3 + rj;
        const int pixoff = hh * WW + ww2;
        float ox = off_buf[(b * 18 + np) * (HH * WW) + pixoff];
        float oy = off_buf[(b * 18 + 9 + np) * (HH * WW) + pixoff];
        float mv = m_buf[(b * 9 + np) * (HH * WW) + pixoff];
        float px = (float)(hh + ri) + ox;
        float py = (float)(ww2 + rj) + oy;
        float fx = floorf(px), fy = floorf(py);
        float ltx = fminf(fmaxf(fx, 0.f), 129.f);
        float lty = fminf(fmaxf(fy, 0.f), 129.f);
        float rbx = fminf(fmaxf(fx + 1.f, 0.f), 129.f);
        float rby = fminf(fmaxf(fy + 1.f, 0.f), 129.f);
        float pxc = fminf(fmaxf(px, 0.f), 129.f);
        float pyc = fminf(fmaxf(py, 0.f), 129.f);
        float glt = (1.f + ltx - pxc) * (1.f + lty - pyc);
        float grb = (1.f - rbx + pxc) * (1.f - rby + pyc);
        float glb = (1.f + ltx - pxc) * (1.f - rby + pyc);
        float grt = (1.f - rbx + pxc) * (1.f + lty - pyc);
        int ix0 = (int)ltx, iy0 = (int)lty, ix1 = (int)rbx, iy1 = (int)rby;
        float x_lt = xpb[(size_t)(ix0 * HP + iy0) * 64];
        float x_rb = xpb[(size_t)(ix1 * HP + iy1) * 64];
        float x_lb = xpb[(size_t)(ix0 * HP + iy1) * 64];
        float x_rt = xpb[(size_t)(ix1 * HP + iy0) * 64];
        float sv = glt * x_lt + grb * x_rb + glb * x_lb + grt * x_rt;
        const int t9 = i3 * 3 + j3;
        float pv = (float)Pp[t9 * 64 + c];
        res += pv * (sv * mv);
      }
    }
    smem[c][pl] = res;
  }
  __syncthreads();

  // coalesced write: thread -> (channel c2, 4 consecutive w)
  const int c2 = tid >> 2;
  const int wi = (tid & 3) * 4;
  f32x4 v;
#pragma unroll
  for (int i = 0; i < 4; ++i) v[i] = smem[c2][wi + i];
  *reinterpret_cast<f32x4*>(out + ((size_t)(b * 64 + c2) * HH + h) * WW + w0 + wi) = v;
}

// ---------------------------------------------------------------------------
extern "C" void kernel_launch(void* const* d_in, const int* in_sizes, int n_in,
                              void* d_out, int out_size, void* d_ws, size_t ws_size,
                              hipStream_t stream) {
  (void)in_sizes; (void)n_in; (void)out_size; (void)ws_size;
  const float* fs  = (const float*)d_in[0];
  const float* ctx = (const float*)d_in[1];
  const float* x   = (const float*)d_in[2];
  const float* pw  = (const float*)d_in[3];
  const float* pb  = (const float*)d_in[4];
  const float* fw  = (const float*)d_in[5];
  const float* fb  = (const float*)d_in[6];
  const float* mw  = (const float*)d_in[7];
  const float* mb  = (const float*)d_in[8];

  char* ws = (char*)d_ws;
  bf16*  ctx_t = (bf16*)(ws);                   //  8,652,800
  bf16*  Bf    = (bf16*)(ws + 8652800);         //    663,552
  float* offb  = (float*)(ws + 9316352);        //  4,718,592
  float* mbuf  = (float*)(ws + 14034944);       //  2,359,296
  bf16*  Bf2   = (bf16*)(ws + 16394240);        //     36,864
  float* xp    = (float*)(ws + 16431104);       // 17,318,400 (4*130*130*64*4)
  bf16*  fs_t  = (bf16*)(ws + 16431104);        //  8,652,800 — overlaps xp; dead
                                                //  before xp is built
  bf16*  Pg    = (bf16*)(ws + 33749504);        // 37,748,736 (2*16384*576*2)
                                                // total 71,498,240

  hipMemsetAsync(ctx_t, 0, 8652800, stream);
  hipMemsetAsync((void*)fs_t, 0, 8652800, stream);

  transpose_pad<<<dim3(2, 128, 4), 256, 0, stream>>>(fs, fs_t);
  transpose_pad<<<dim3(2, 128, 4), 256, 0, stream>>>(ctx, ctx_t);
  build_bfrag<<<162, 256, 0, stream>>>(fw, 576, (const float*)nullptr, 0, Bf, 36);
  build_bfrag<<<9, 256, 0, stream>>>(pw, 18, mw, 9, Bf2, 2);
  conv_offm<<<256, 256, 0, stream>>>(fs_t, Bf2, pb, mb, offb, mbuf);
  // fs_t dead; build xp (f32, padded, channel-last) in its place
  hipMemsetAsync((void*)xp, 0, 17318400, stream);
  transpose_pad_f32<<<dim3(2, 128, 4), 256, 0, stream>>>(x, xp);

  for (int b0 = 0; b0 < 4; b0 += 2) {
    gemm_psf<<<dim3(128, 4), 256, 0, stream>>>(ctx_t, Bf, fb, Pg, b0);
    sampler<<<2048, 256, 0, stream>>>(Pg, xp, offb, mbuf, (float*)d_out, b0);
  }
}

// Round 4
// 251.553 us; speedup vs baseline: 2.0204x; 2.0204x over previous
//
#include <hip/hip_runtime.h>

typedef __bf16 bf16;
typedef __bf16 bf16x8 __attribute__((ext_vector_type(8)));
typedef unsigned short u16x8 __attribute__((ext_vector_type(8)));
typedef float f32x4 __attribute__((ext_vector_type(4)));

#define HH 128
#define WW 128
#define HP 130

// ---------------------------------------------------------------------------
// One launch transposes all three inputs: z<4 fs->fs_t(bf16), z<8 ctx->ctx_t,
// z<12 x->xp(f32). Rings pre-zeroed by a single memset.
// ---------------------------------------------------------------------------
__global__ __launch_bounds__(256) void transpose_all(
    const float* __restrict__ fs, const float* __restrict__ ctx,
    const float* __restrict__ x, bf16* __restrict__ fs_t,
    bf16* __restrict__ ctx_t, float* __restrict__ xp) {
  __shared__ float tile[64][65];
  const int z = blockIdx.z;
  const int b = z & 3, which = z >> 2;
  const float* in = which == 0 ? fs : (which == 1 ? ctx : x);
  const int y = blockIdx.y, x0 = blockIdx.x * 64;
  const int tid = threadIdx.x;
#pragma unroll
  for (int pass = 0; pass < 16; ++pass) {
    int ci = pass * 4 + (tid >> 6), xx = tid & 63;
    tile[ci][xx] = in[((b * 64 + ci) * HH + y) * WW + x0 + xx];
  }
  __syncthreads();
  if (which == 2) {
#pragma unroll
    for (int pass = 0; pass < 16; ++pass) {
      int xx = pass * 4 + (tid >> 6), ci = tid & 63;
      xp[((size_t)(b * HP + y + 1) * HP + (x0 + xx + 1)) * 64 + ci] = tile[ci][xx];
    }
  } else {
    bf16* out = which ? ctx_t : fs_t;
#pragma unroll
    for (int pass = 0; pass < 16; ++pass) {
      int xx = pass * 4 + (tid >> 6), ci = tid & 63;
      out[((size_t)(b * HP + y + 1) * HP + (x0 + xx + 1)) * 64 + ci] = (bf16)tile[ci][xx];
    }
  }
}

// ---------------------------------------------------------------------------
// PSF weights -> B-frag layout [cc][kc(18)][nt(9)][lane][8], COLUMN-PERMUTED:
// GEMM column n' = t9*64 + c corresponds to filter channel n = c*9 + t9.
// ---------------------------------------------------------------------------
__global__ void build_bfrag_psf(const float* __restrict__ fw, bf16* __restrict__ dst) {
  int idx = blockIdx.x * 256 + threadIdx.x;   // total 4*18*9*64 = 41472
  int lane = idx & 63;
  int nt = (idx >> 6) % 9;
  int kc = ((idx >> 6) / 9) % 18;
  int cc = (idx >> 6) / 162;
  int np = cc * 144 + nt * 16 + (lane & 15);  // permuted column
  int n = (np & 63) * 9 + (np >> 6);          // original filter channel
  int q = lane >> 4;
  bf16x8 v;
#pragma unroll
  for (int j = 0; j < 8; ++j) {
    int k = kc * 32 + q * 8 + j;
    int tap = k >> 6, ci = k & 63;
    v[j] = (bf16)fw[(n * 64 + ci) * 9 + tap];
  }
  *reinterpret_cast<bf16x8*>(dst + (size_t)idx * 8) = v;
}

// offset+mask weights -> [kc(18)][nt(2)][lane][8] (no permutation)
__global__ void build_bfrag_offm(const float* __restrict__ pw,
                                 const float* __restrict__ mw,
                                 bf16* __restrict__ dst) {
  int idx = blockIdx.x * 256 + threadIdx.x;   // total 18*2*64 = 2304
  int lane = idx & 63;
  int nt = (idx >> 6) & 1;
  int kc = (idx >> 6) >> 1;
  int n = nt * 16 + (lane & 15);
  int q = lane >> 4;
  bf16x8 v;
#pragma unroll
  for (int j = 0; j < 8; ++j) {
    int k = kc * 32 + q * 8 + j;
    int tap = k >> 6, ci = k & 63;
    float w = 0.f;
    if (n < 18) w = pw[(n * 64 + ci) * 9 + tap];
    else if (n < 27) w = mw[((n - 18) * 64 + ci) * 9 + tap];
    v[j] = (bf16)w;
  }
  *reinterpret_cast<bf16x8*>(dst + (size_t)idx * 8) = v;
}

// ---------------------------------------------------------------------------
// Mega kernel: blocks [0,offmN) do the offset/mask conv (all 4 b);
// blocks [offmN,..) do the PSF GEMM for b0..b0+1 with per-tap LDS B-staging.
// ---------------------------------------------------------------------------
__global__ __launch_bounds__(256, 2) void conv_mega(
    const bf16* __restrict__ ctx_t, const bf16* __restrict__ fs_t,
    const bf16* __restrict__ Bf, const bf16* __restrict__ Bf2,
    const float* __restrict__ fb, const float* __restrict__ pb,
    const float* __restrict__ mb, bf16* __restrict__ Pg,
    float* __restrict__ OM, int b0, int offmN) {
  __shared__ __align__(16) char smem[59904];  // apatch 41472 + Bsm 18432
  ushort* apatch = (ushort*)smem;
  const int tid = threadIdx.x;
  const int lane = tid & 63, wv = tid >> 6;
  const int q = lane >> 4, col = lane & 15;
  const int bid = blockIdx.x;

  if ((int)bid < offmN) {
    // ---------------- offset/mask conv ----------------
    const int b = bid >> 6, t = bid & 63;
    const int h0 = (t >> 3) * 16, w0 = (t & 7) * 16;
    const ushort* Atu = (const ushort*)fs_t;
#pragma unroll
    for (int it = 0; it < 11; ++it) {
      int flat = it * 256 + tid;
      if (flat < 2592) {
        int px = flat >> 3, c8 = flat & 7;
        int py = px / 18, pxx = px - py * 18;
        u16x8 v = *(const u16x8*)(Atu + ((size_t)((b * HP + h0 + py) * HP + (w0 + pxx))) * 64 + c8 * 8);
        *(u16x8*)(apatch + px * 64 + ((c8 ^ (px & 7)) * 8)) = v;
      }
    }
    __syncthreads();
    f32x4 acc[4][2];
#pragma unroll
    for (int s = 0; s < 4; ++s) {
      acc[s][0] = (f32x4){0.f, 0.f, 0.f, 0.f};
      acc[s][1] = (f32x4){0.f, 0.f, 0.f, 0.f};
    }
    const bf16* bl = Bf2 + lane * 8;
#pragma unroll
    for (int dh = 0; dh < 3; ++dh)
#pragma unroll
      for (int dw = 0; dw < 3; ++dw) {
        const int tap = dh * 3 + dw;
        bf16x8 a[4][2];
#pragma unroll
        for (int s = 0; s < 4; ++s) {
          int p = (s * 4 + wv + dh) * 18 + (col + dw);
#pragma unroll
          for (int hf = 0; hf < 2; ++hf) {
            int ch = (hf * 4 + q) ^ (p & 7);
            a[s][hf] = *(const bf16x8*)((const bf16*)apatch + p * 64 + ch * 8);
          }
        }
#pragma unroll
        for (int hf = 0; hf < 2; ++hf)
#pragma unroll
          for (int nt = 0; nt < 2; ++nt) {
            bf16x8 bb = *(const bf16x8*)(bl + (size_t)(((tap * 2 + hf) * 2 + nt) * 512));
#pragma unroll
            for (int s = 0; s < 4; ++s)
              acc[s][nt] = __builtin_amdgcn_mfma_f32_16x16x32_bf16(a[s][hf], bb, acc[s][nt], 0, 0, 0);
          }
      }
    float* OMb = OM + (size_t)b * 16384 * 32;
#pragma unroll
    for (int nt = 0; nt < 2; ++nt) {
      int n = nt * 16 + col;
#pragma unroll
      for (int s = 0; s < 4; ++s) {
        int h = h0 + s * 4 + wv;
#pragma unroll
        for (int j = 0; j < 4; ++j) {
          int w = w0 + q * 4 + j;
          float v = acc[s][nt][j];
          float r;
          if (n < 18) r = v + pb[n];
          else if (n < 27) { float z = v + mb[n - 18]; r = 1.f / (1.f + __expf(-z)); }
          else r = 0.f;
          OMb[(size_t)(h * WW + w) * 32 + n] = r;
        }
      }
    }
    return;
  }

  // ---------------- PSF GEMM ----------------
  const int pid = bid - offmN;
  const int cc = pid & 3;
  const int rest = pid >> 2;
  const int brel = rest >> 6;
  const int b = b0 + brel;
  const int t = rest & 63;
  const int h0 = (t >> 3) * 16, w0 = (t & 7) * 16;
  bf16* Bsm = (bf16*)(smem + 41472);

  const ushort* Atu = (const ushort*)ctx_t;
#pragma unroll
  for (int it = 0; it < 11; ++it) {
    int flat = it * 256 + tid;
    if (flat < 2592) {
      int px = flat >> 3, c8 = flat & 7;
      int py = px / 18, pxx = px - py * 18;
      u16x8 v = *(const u16x8*)(Atu + ((size_t)((b * HP + h0 + py) * HP + (w0 + pxx))) * 64 + c8 * 8);
      *(u16x8*)(apatch + px * 64 + ((c8 ^ (px & 7)) * 8)) = v;
    }
  }
  __syncthreads();

  f32x4 acc[4][9];
#pragma unroll
  for (int s = 0; s < 4; ++s)
#pragma unroll
    for (int n = 0; n < 9; ++n) acc[s][n] = (f32x4){0.f, 0.f, 0.f, 0.f};

  const char* BfC = (const char*)Bf + (size_t)cc * 165888;  // 18 kc * 9216 B

  for (int tap = 0; tap < 9; ++tap) {
    __syncthreads();   // previous tap's Bsm reads done
    {
      const char* gs = BfC + tap * 18432;
      char* ld = smem + 41472;
#pragma unroll
      for (int it = 0; it < 5; ++it) {
        int flat = it * 256 + wv * 64;     // wave-uniform chunk base
        if (flat < 1152) {
          __builtin_amdgcn_global_load_lds(
              (const __attribute__((address_space(1))) void*)(gs + (size_t)(flat + lane) * 16),
              (__attribute__((address_space(3))) void*)(ld + flat * 16), 16, 0, 0);
        }
      }
    }
    __syncthreads();   // drains vmcnt -> Bsm ready

    const int dh = tap >= 6 ? 2 : (tap >= 3 ? 1 : 0);
    const int dw = tap - dh * 3;
    bf16x8 a[4][2];
#pragma unroll
    for (int s = 0; s < 4; ++s) {
      int p = (s * 4 + wv + dh) * 18 + (col + dw);
#pragma unroll
      for (int hf = 0; hf < 2; ++hf) {
        int ch = (hf * 4 + q) ^ (p & 7);
        a[s][hf] = *(const bf16x8*)((const bf16*)apatch + p * 64 + ch * 8);
      }
    }
#pragma unroll
    for (int hf = 0; hf < 2; ++hf) {
      const bf16* bp = Bsm + (size_t)(hf * 9) * 512 + lane * 8;
#pragma unroll
      for (int nt = 0; nt < 9; ++nt) {
        bf16x8 bb = *(const bf16x8*)(bp + nt * 512);
#pragma unroll
        for (int s = 0; s < 4; ++s)
          acc[s][nt] = __builtin_amdgcn_mfma_f32_16x16x32_bf16(a[s][hf], bb, acc[s][nt], 0, 0, 0);
      }
    }
  }

  // epilogue: P[px][n'] (n' = t9*64 + c), bias via inverse permutation
  bf16* Pp = Pg + (size_t)brel * 16384 * 576;
#pragma unroll
  for (int nt = 0; nt < 9; ++nt) {
    int np = cc * 144 + nt * 16 + col;
    float bias = fb[(np & 63) * 9 + (np >> 6)];
#pragma unroll
    for (int s = 0; s < 4; ++s) {
      int h = h0 + s * 4 + wv;
#pragma unroll
      for (int j = 0; j < 4; ++j) {
        int w = w0 + q * 4 + j;
        Pp[(size_t)(h * WW + w) * 576 + np] = (bf16)(acc[s][nt][j] + bias);
      }
    }
  }
}

// ---------------------------------------------------------------------------
// Sampler: wave = pixel, lane = channel. Coalesced 256B xp gathers, 128B P
// reads, scalar OM reads. Output through small LDS transpose (stride 21).
// ---------------------------------------------------------------------------
__global__ __launch_bounds__(256, 4) void sampler(
    const bf16* __restrict__ Pg, const float* __restrict__ xp,
    const float* __restrict__ OM, float* __restrict__ out, int b0) {
  __shared__ float smem[64][21];
  const int tid = threadIdx.x;
  const int wv = tid >> 6, c = tid & 63;
  const int blk = blockIdx.x;
  const int brel = blk >> 10;
  const int b = b0 + brel;
  const int h = (blk >> 3) & 127;
  const int w0 = (blk & 7) * 16;

  const float* xpb = xp + (size_t)b * (HP * HP * 64) + c;
  const float* OMb = OM + (size_t)b * 16384 * 32;
  const bf16* Pbase = Pg + ((size_t)brel * 16384 + h * WW + w0) * 576;

#pragma unroll
  for (int k = 0; k < 4; ++k) {
    const int pl = wv * 4 + k;
    const int w = w0 + pl;
    const bf16* Pp = Pbase + (size_t)pl * 576;
    float res = 0.f;
#pragma unroll
    for (int i3 = 0; i3 < 3; ++i3) {
#pragma unroll
      for (int j3 = 0; j3 < 3; ++j3) {
        const int dh = (i3 == 0) ? -1 : 0, ri = (i3 == 0) ? 2 : (i3 - 1);
        const int dw = (j3 == 0) ? -1 : 0, rj = (j3 == 0) ? 2 : (j3 - 1);
        const int hh = h + dh, ww2 = w + dw;
        if (hh < 0 || ww2 < 0) continue;     // wave-uniform
        const int np = ri * 3 + rj;
        const float* omp = OMb + (size_t)(hh * WW + ww2) * 32;
        float ox = omp[np], oy = omp[9 + np], mv = omp[18 + np];
        float px = (float)(hh + ri) + ox;
        float py = (float)(ww2 + rj) + oy;
        float fx = floorf(px), fy = floorf(py);
        float ltx = fminf(fmaxf(fx, 0.f), 129.f);
        float lty = fminf(fmaxf(fy, 0.f), 129.f);
        float rbx = fminf(fmaxf(fx + 1.f, 0.f), 129.f);
        float rby = fminf(fmaxf(fy + 1.f, 0.f), 129.f);
        float pxc = fminf(fmaxf(px, 0.f), 129.f);
        float pyc = fminf(fmaxf(py, 0.f), 129.f);
        float glt = (1.f + ltx - pxc) * (1.f + lty - pyc);
        float grb = (1.f - rbx + pxc) * (1.f - rby + pyc);
        float glb = (1.f + ltx - pxc) * (1.f - rby + pyc);
        float grt = (1.f - rbx + pxc) * (1.f + lty - pyc);
        int ix0 = (int)ltx, iy0 = (int)lty, ix1 = (int)rbx, iy1 = (int)rby;
        float x_lt = xpb[(size_t)(ix0 * HP + iy0) * 64];
        float x_rb = xpb[(size_t)(ix1 * HP + iy1) * 64];
        float x_lb = xpb[(size_t)(ix0 * HP + iy1) * 64];
        float x_rt = xpb[(size_t)(ix1 * HP + iy0) * 64];
        float sv = glt * x_lt + grb * x_rb + glb * x_lb + grt * x_rt;
        float pv = (float)Pp[(i3 * 3 + j3) * 64 + c];
        res += pv * (sv * mv);
      }
    }
    smem[c][pl] = res;
  }
  __syncthreads();
  const int c2 = tid >> 2;
  const int wi = (tid & 3) * 4;
  f32x4 v;
#pragma unroll
  for (int i = 0; i < 4; ++i) v[i] = smem[c2][wi + i];
  *reinterpret_cast<f32x4*>(out + ((size_t)(b * 64 + c2) * HH + h) * WW + w0 + wi) = v;
}

// ---------------------------------------------------------------------------
extern "C" void kernel_launch(void* const* d_in, const int* in_sizes, int n_in,
                              void* d_out, int out_size, void* d_ws, size_t ws_size,
                              hipStream_t stream) {
  (void)in_sizes; (void)n_in; (void)out_size; (void)ws_size;
  const float* fs  = (const float*)d_in[0];
  const float* ctx = (const float*)d_in[1];
  const float* x   = (const float*)d_in[2];
  const float* pw  = (const float*)d_in[3];
  const float* pb  = (const float*)d_in[4];
  const float* fw  = (const float*)d_in[5];
  const float* fb  = (const float*)d_in[6];
  const float* mw  = (const float*)d_in[7];
  const float* mb  = (const float*)d_in[8];

  char* ws = (char*)d_ws;
  bf16*  ctx_t = (bf16*)(ws);                   //  8,652,800
  bf16*  fs_t  = (bf16*)(ws + 8652800);         //  8,652,800
  float* xp    = (float*)(ws + 17305600);       // 17,305,600
  bf16*  Bf    = (bf16*)(ws + 34611200);        //    663,552
  bf16*  Bf2   = (bf16*)(ws + 35274752);        //     36,864
  float* OM    = (float*)(ws + 35311616);       //  8,388,608
  bf16*  Pg    = (bf16*)(ws + 43700224);        // 37,748,736  (2 batches)
                                                // total 81,448,960

  // zero padded rings of ctx_t/fs_t/xp in one shot
  hipMemsetAsync(ws, 0, 34611200, stream);
  transpose_all<<<dim3(2, 128, 12), 256, 0, stream>>>(fs, ctx, x, fs_t, ctx_t, xp);
  build_bfrag_psf<<<162, 256, 0, stream>>>(fw, Bf);
  build_bfrag_offm<<<9, 256, 0, stream>>>(pw, mw, Bf2);

  // launch 1: offm (256 blocks, all b) + PSF GEMM b0..1 (512 blocks)
  conv_mega<<<768, 256, 0, stream>>>(ctx_t, fs_t, Bf, Bf2, fb, pb, mb, Pg, OM, 0, 256);
  sampler<<<2048, 256, 0, stream>>>(Pg, xp, OM, (float*)d_out, 0);
  // launch 2: PSF GEMM b2..3 only
  conv_mega<<<512, 256, 0, stream>>>(ctx_t, fs_t, Bf, Bf2, fb, pb, mb, Pg, OM, 2, 0);
  sampler<<<2048, 256, 0, stream>>>(Pg, xp, OM, (float*)d_out, 2);
}